// Round 6
// baseline (1088.976 us; speedup 1.0000x reference)
//
#include <hip/hip_runtime.h>
#include <math.h>

#define HDIM 512
#define NHEAD 8
#define NLAYER 6
#define SEQ 2048
#define BATCH 2
#define DHEAD 64
#define TOKENS (BATCH*SEQ)
#define FFND (4*HDIM)
#define QSTR 1536   // fused QKV row stride

typedef unsigned short u16;
typedef __attribute__((ext_vector_type(8))) short short8;
typedef __attribute__((ext_vector_type(4))) float f32x4;

__device__ __forceinline__ u16 f2b(float f) {
  unsigned u = __float_as_uint(f);
  u += 0x7FFFu + ((u >> 16) & 1u);
  return (u16)(u >> 16);
}

__device__ __forceinline__ void gload_lds16(const u16* g, u16* l) {
  __builtin_amdgcn_global_load_lds((const __attribute__((address_space(1))) void*)g,
                                   (__attribute__((address_space(3))) void*)l, 16, 0, 0);
}

// ---------------- embed + positional encoding ----------------
__global__ void embed_pe(const int* __restrict__ src, const float* __restrict__ emb,
                         float* __restrict__ X, u16* __restrict__ Xb) {
  int tok = blockIdx.x;
  int lane = threadIdx.x;           // 64 threads
  int s = tok & (SEQ - 1);
  int c0 = lane * 8;
  const float* e = emb + (long)src[tok] * HDIM + c0;
  float v[8];
#pragma unroll
  for (int j = 0; j < 8; j++) {
    int c = c0 + j;
    float arg = (float)s * exp2f(-(float)(c & ~1) * 0.02595256917f);
    v[j] = e[j] + ((c & 1) ? cosf(arg) : sinf(arg));
  }
  float* xp = X + (long)tok * HDIM + c0;
#pragma unroll
  for (int j = 0; j < 8; j++) xp[j] = v[j];
  u16 hb[8];
#pragma unroll
  for (int j = 0; j < 8; j++) hb[j] = f2b(v[j]);
  uint4 pk;
  pk.x = hb[0] | ((unsigned)hb[1] << 16);
  pk.y = hb[2] | ((unsigned)hb[3] << 16);
  pk.z = hb[4] | ((unsigned)hb[5] << 16);
  pk.w = hb[6] | ((unsigned)hb[7] << 16);
  *(uint4*)(Xb + (long)tok * HDIM + c0) = pk;
}

// ---------------- mask int -> float {0,1} ----------------
__global__ void mask2f(const int* __restrict__ mask, float* __restrict__ maskf) {
  int i = blockIdx.x * 256 + threadIdx.x;
  maskf[i] = (mask[i] == 0) ? 0.0f : 1.0f;
}

// ---------------- per-layer weight prep: fp32 [K][N] -> bf16 [N][K] ----------------
__global__ __launch_bounds__(256) void prep_weights(
    const float* __restrict__ Wq, const float* __restrict__ Wk, const float* __restrict__ Wv,
    const float* __restrict__ Wo, const float* __restrict__ W1, const float* __restrict__ W2,
    const float* __restrict__ bq, const float* __restrict__ bk, const float* __restrict__ bv,
    u16* __restrict__ Wqkvt, u16* __restrict__ Wot, u16* __restrict__ W1t, u16* __restrict__ W2t,
    float* __restrict__ bqkv) {
  int t = blockIdx.x;
  int tid = threadIdx.x;
  if (t == 768) {
    for (int i = tid; i < 1536; i += 256)
      bqkv[i] = (i < 512) ? bq[i] : (i < 1024) ? bk[i - 512] : bv[i - 1024];
    return;
  }
  const float* src; u16* dst; int K, N, kt, nt; long drow0 = 0;
  if (t < 192)      { int m = t / 64, r = t % 64; src = (m==0)?Wq:(m==1)?Wk:Wv; dst = Wqkvt; drow0 = (long)m*512; K=512;  N=512;  kt=r/8;  nt=r%8; }
  else if (t < 256) { int r = t - 192; src = Wo; dst = Wot; K=512;  N=512;  kt=r/8;  nt=r%8; }
  else if (t < 512) { int r = t - 256; src = W1; dst = W1t; K=512;  N=2048; kt=r/32; nt=r%32; }
  else              { int r = t - 512; src = W2; dst = W2t; K=2048; N=512;  kt=r/8;  nt=r%8; }
  __shared__ __align__(16) u16 Lt[64 * 72];
  int kl = tid >> 2;                 // local k row 0..63
#pragma unroll
  for (int rr = 0; rr < 4; rr++) {
    int cl = (tid & 3) * 4 + rr * 16;  // local n col
    float4 v = *(const float4*)(src + (long)(kt * 64 + kl) * N + nt * 64 + cl);
    Lt[(cl + 0) * 72 + kl] = f2b(v.x);
    Lt[(cl + 1) * 72 + kl] = f2b(v.y);
    Lt[(cl + 2) * 72 + kl] = f2b(v.z);
    Lt[(cl + 3) * 72 + kl] = f2b(v.w);
  }
  __syncthreads();
  int nl = tid >> 2;                 // out row (n) 0..63
  int kc = (tid & 3) * 16;           // out col chunk (k)
  u16* dp = dst + (drow0 + nt * 64 + nl) * (long)K + kt * 64 + kc;
  *(uint4*)dp       = *(const uint4*)&Lt[nl * 72 + kc];
  *(uint4*)(dp + 8) = *(const uint4*)&Lt[nl * 72 + kc + 8];
}

// ---------------- V transpose: QKV V-region -> Vtb[b][h][d][S] ----------------
__global__ __launch_bounds__(256) void vtranspose(const u16* __restrict__ QKV,
                                                  u16* __restrict__ Vtb) {
  __shared__ __align__(16) u16 Lt[64 * 72];
  int tid = threadIdx.x;
  int bh = blockIdx.y, b = bh >> 3, h = bh & 7;
  int s0 = blockIdx.x * 64;
  const u16* vsrc = QKV + (long)(b * SEQ + s0) * QSTR + 1024 + h * DHEAD;
  int key = tid >> 2, dc = (tid & 3) * 16;
  const u16* vp = vsrc + (long)key * QSTR + dc;
  uint4 v0 = *(const uint4*)vp;
  uint4 v1 = *(const uint4*)(vp + 8);
  unsigned vr[8] = { v0.x, v0.y, v0.z, v0.w, v1.x, v1.y, v1.z, v1.w };
#pragma unroll
  for (int j = 0; j < 8; j++) {
    Lt[(dc + 2 * j) * 72 + key]     = (u16)vr[j];
    Lt[(dc + 2 * j + 1) * 72 + key] = (u16)(vr[j] >> 16);
  }
  __syncthreads();
  int d = tid >> 2, kc = (tid & 3) * 16;
  u16* dst = Vtb + ((long)bh * DHEAD + d) * SEQ + s0 + kc;
  *(uint4*)dst       = *(const uint4*)&Lt[d * 72 + kc];
  *(uint4*)(dst + 8) = *(const uint4*)&Lt[d * 72 + kc + 8];
}

// ---------------- m97-style bf16 TN GEMM, double-buffered, optional split-K ----------------
template <int BN, int KSPLIT, bool RELU, bool WF32, bool WB16>
__global__ __launch_bounds__(256) void gemm_tn(const u16* __restrict__ A,
                                               const u16* __restrict__ Bt,
                                               const float* __restrict__ bias,
                                               float* __restrict__ Cf,
                                               u16* __restrict__ Cb,
                                               int M, int N, int K) {
  constexpr int NF = BN / 32;                 // n-frags per wave
  __shared__ __align__(16) u16 As[2][128 * 32];
  __shared__ __align__(16) u16 Bs[2][BN * 32];
  int tid = threadIdx.x;
  int wave = tid >> 6, lane = tid & 63;
  int ln = lane & 15, hi = lane >> 4;
  int wm = wave >> 1, wn = wave & 1;
  int m0 = blockIdx.y * 128, n0 = blockIdx.x * BN;
  int z = (KSPLIT > 1) ? blockIdx.z : 0;
  int Ks = K / KSPLIT;
  const u16* Ab = A + z * Ks;
  const u16* Bb = Bt + z * Ks;

  f32x4 acc[4][NF] = {};

  int srow = lane >> 2;        // 0..15
  int skc  = (lane & 3) * 8;   // k-chunk within 32

  auto issue = [&](int kt, int buf) {
    int k0 = kt * 32;
#pragma unroll
    for (int j = 0; j < 2; j++) {
      int row = (wave * 2 + j) * 16 + srow;
      gload_lds16(Ab + (long)(m0 + row) * K + k0 + skc, &As[buf][row * 32 + skc]);
    }
#pragma unroll
    for (int j = 0; j < BN / 64; j++) {
      int row = (wave * (BN / 64) + j) * 16 + srow;
      gload_lds16(Bb + (long)(n0 + row) * K + k0 + skc, &Bs[buf][row * 32 + skc]);
    }
  };

  int NT = Ks / 32;
  issue(0, 0);
  __syncthreads();
  for (int kt = 0; kt < NT; kt++) {
    int buf = kt & 1;
    if (kt + 1 < NT) issue(kt + 1, buf ^ 1);
    short8 af[4], bf[NF];
#pragma unroll
    for (int mt = 0; mt < 4; mt++)
      af[mt] = *(const short8*)&As[buf][(wm * 64 + mt * 16 + ln) * 32 + 8 * hi];
#pragma unroll
    for (int nt = 0; nt < NF; nt++)
      bf[nt] = *(const short8*)&Bs[buf][(wn * (BN / 2) + nt * 16 + ln) * 32 + 8 * hi];
#pragma unroll
    for (int mt = 0; mt < 4; mt++)
#pragma unroll
      for (int nt = 0; nt < NF; nt++)
        acc[mt][nt] = __builtin_amdgcn_mfma_f32_16x16x32_bf16(af[mt], bf[nt], acc[mt][nt], 0, 0, 0);
    __syncthreads();
  }

  float* Cz = WF32 ? (Cf + (long)z * M * N) : nullptr;
#pragma unroll
  for (int mt = 0; mt < 4; mt++)
#pragma unroll
    for (int nt = 0; nt < NF; nt++)
#pragma unroll
      for (int r = 0; r < 4; r++) {
        int row = m0 + wm * 64 + mt * 16 + hi * 4 + r;
        int col = n0 + wn * (BN / 2) + nt * 16 + ln;
        float v = acc[mt][nt][r];
        if (KSPLIT == 1 || z == 0) v += bias[col];
        if (RELU) v = fmaxf(v, 0.0f);
        if (WF32) Cz[(long)row * N + col] = v;
        if (WB16) Cb[(long)row * N + col] = f2b(v);
      }
}

// ---------------- flash attention: S^T form, packed P writes, key-split z=2 ----------------
// grid (SEQ/64, BATCH*NHEAD, 2), 256 thr. Wave w owns q-rows q0..q0+15.
// QK^T computed with swapped operands (A=K,B=Q) -> lane holds S^T[key=hi*4+r][q=ln]:
// the 4 r-values are CONSECUTIVE keys -> one aligned ds_write_b64 per frag (no b16
// scatter, bank-balanced at stride 80). Mask applied multiplicatively (maskf).
// Output: unnormalized fp32 O-partial + l-partial per z; combined downstream.
__global__ __launch_bounds__(256) void attention(const u16* __restrict__ QKV,
                                                 const u16* __restrict__ Vtb,
                                                 const float* __restrict__ maskf,
                                                 float* __restrict__ Opart,
                                                 float* __restrict__ Lpart) {
  __shared__ __align__(16) u16 Ks[2][2][64 * 32];  // [buf][d-half][key][32]
  __shared__ __align__(16) u16 Vs[2][2][64 * 32];  // [buf][key-half][d][32]
  __shared__ __align__(16) u16 P[4 * 16 * 80];     // per-wave P[q][key], stride 80
  int tid = threadIdx.x, w = tid >> 6, lane = tid & 63;
  int ln = lane & 15, hi = lane >> 4;
  int bh = blockIdx.y, b = bh >> 3, h = bh & 7;
  int z = blockIdx.z;
  int q0 = blockIdx.x * 64 + w * 16;
  const u16* qbase = QKV + (long)b * SEQ * QSTR + h * DHEAD;
  const u16* kbase = qbase + 512;
  const u16* vtbase = Vtb + (long)bh * DHEAD * SEQ;
  const float* mbase = maskf + b * SEQ + z * (SEQ / 2);
  u16* Pw = P + w * 16 * 80;

  short8 qf[2];
#pragma unroll
  for (int ks = 0; ks < 2; ks++)
    qf[ks] = *(const short8*)(qbase + (long)(q0 + ln) * QSTR + ks * 32 + 8 * hi);

  f32x4 o[4] = {};
  float lsum = 0.0f;

  int srow = w * 16 + (lane >> 2);   // 0..63 across waves
  int sc = (lane & 3) * 8;           // 8-u16 chunk

  auto issue = [&](int t, int buf) {
    long kk = (long)z * (SEQ / 2) + t * 64;
    const u16* kg = kbase + (kk + srow) * QSTR + sc;
    gload_lds16(kg,      &Ks[buf][0][srow * 32 + sc]);
    gload_lds16(kg + 32, &Ks[buf][1][srow * 32 + sc]);
    const u16* vg = vtbase + (long)srow * SEQ + kk + sc;
    gload_lds16(vg,      &Vs[buf][0][srow * 32 + sc]);
    gload_lds16(vg + 32, &Vs[buf][1][srow * 32 + sc]);
  };

  const int NT = (SEQ / 2) / 64;
  issue(0, 0);
  __syncthreads();
  for (int t = 0; t < NT; t++) {
    int buf = t & 1;
    if (t + 1 < NT) issue(t + 1, buf ^ 1);
    int k0 = t * 64;

    // S^T = K @ Q^T : A-frag = K rows (same LDS bytes as before), B-frag = qf.
    f32x4 s[4] = {};
#pragma unroll
    for (int ks = 0; ks < 2; ks++)
#pragma unroll
      for (int nt = 0; nt < 4; nt++) {
        short8 kf = *(const short8*)&Ks[buf][ks][(nt * 16 + ln) * 32 + 8 * hi];
        s[nt] = __builtin_amdgcn_mfma_f32_16x16x32_bf16(kf, qf[ks], s[nt], 0, 0, 0);
      }
#pragma unroll
    for (int nt = 0; nt < 4; nt++) {
      float4 mf = *(const float4*)(mbase + k0 + nt * 16 + hi * 4);
      float mfa[4] = { mf.x, mf.y, mf.z, mf.w };
      u16 hb[4];
#pragma unroll
      for (int r = 0; r < 4; r++) {
        float p = __expf(s[nt][r] * 0.125f) * mfa[r];
        lsum += p;
        hb[r] = f2b(p);
      }
      uint2 pk;
      pk.x = hb[0] | ((unsigned)hb[1] << 16);
      pk.y = hb[2] | ((unsigned)hb[3] << 16);
      *(uint2*)&Pw[ln * 80 + nt * 16 + hi * 4] = pk;
    }
    // O += P @ V  (A-frag read of P[q][key]; same-wave ordering via lgkmcnt)
    short8 pa[2];
#pragma unroll
    for (int ka = 0; ka < 2; ka++)
      pa[ka] = *(const short8*)&Pw[ln * 80 + ka * 32 + 8 * hi];
#pragma unroll
    for (int nt = 0; nt < 4; nt++) {
      short8 bv0 = *(const short8*)&Vs[buf][0][(nt * 16 + ln) * 32 + 8 * hi];
      short8 bv1 = *(const short8*)&Vs[buf][1][(nt * 16 + ln) * 32 + 8 * hi];
      o[nt] = __builtin_amdgcn_mfma_f32_16x16x32_bf16(pa[0], bv0, o[nt], 0, 0, 0);
      o[nt] = __builtin_amdgcn_mfma_f32_16x16x32_bf16(pa[1], bv1, o[nt], 0, 0, 0);
    }
    __syncthreads();
  }

  // l[q=ln]: sum across hi groups (each covered distinct keys)
  lsum += __shfl_xor(lsum, 16);
  lsum += __shfl_xor(lsum, 32);
  if (lane < 16)
    Lpart[(long)z * BATCH * NHEAD * SEQ + (long)bh * SEQ + q0 + ln] = lsum;

  float* obase = Opart + (long)z * TOKENS * HDIM + (long)b * SEQ * HDIM + h * DHEAD;
#pragma unroll
  for (int r = 0; r < 4; r++) {
    int srow2 = q0 + hi * 4 + r;
#pragma unroll
    for (int nt = 0; nt < 4; nt++)
      obase[(long)srow2 * HDIM + nt * 16 + ln] = o[nt][r];
  }
}

// ---------------- combine z-partials: AVb = (O0+O1)/(l0+l1) ----------------
__global__ __launch_bounds__(256) void attn_combine(const float* __restrict__ Opart,
                                                    const float* __restrict__ Lpart,
                                                    u16* __restrict__ AVb) {
  int tid = threadIdx.x, w = tid >> 6, lane = tid & 63;
  int row = blockIdx.x * 4 + w;            // token row
  int b = row >> 11, s = row & (SEQ - 1);
  int c0 = lane * 8, h = c0 >> 6;
  const float* o0 = Opart + (long)row * HDIM + c0;
  const float* o1 = Opart + (long)TOKENS * HDIM + (long)row * HDIM + c0;
  float l0 = Lpart[(long)(b * NHEAD + h) * SEQ + s];
  float l1 = Lpart[(long)BATCH * NHEAD * SEQ + (long)(b * NHEAD + h) * SEQ + s];
  float inv = 1.0f / (l0 + l1);
  float4 a0 = *(const float4*)o0, b0 = *(const float4*)(o0 + 4);
  float4 a1 = *(const float4*)o1, b1 = *(const float4*)(o1 + 4);
  u16 hb[8];
  hb[0] = f2b((a0.x + a1.x) * inv); hb[1] = f2b((a0.y + a1.y) * inv);
  hb[2] = f2b((a0.z + a1.z) * inv); hb[3] = f2b((a0.w + a1.w) * inv);
  hb[4] = f2b((b0.x + b1.x) * inv); hb[5] = f2b((b0.y + b1.y) * inv);
  hb[6] = f2b((b0.z + b1.z) * inv); hb[7] = f2b((b0.w + b1.w) * inv);
  uint4 pk;
  pk.x = hb[0] | ((unsigned)hb[1] << 16);
  pk.y = hb[2] | ((unsigned)hb[3] << 16);
  pk.z = hb[4] | ((unsigned)hb[5] << 16);
  pk.w = hb[6] | ((unsigned)hb[7] << 16);
  *(uint4*)(AVb + (long)row * HDIM + c0) = pk;
}

// ---------------- residual + LayerNorm over summed split-K partials ----------------
__global__ __launch_bounds__(256) void ln_residual(const float* __restrict__ Xin,
                                                   const float* __restrict__ T0,
                                                   const float* __restrict__ T1,
                                                   const float* __restrict__ gamma,
                                                   const float* __restrict__ beta,
                                                   float* __restrict__ Xout,
                                                   u16* __restrict__ Xb) {
  int tid = threadIdx.x, w = tid >> 6, lane = tid & 63;
  int row = blockIdx.x * 4 + w;
  const float* t0 = T0 + (long)row * HDIM;
  const float* t1 = T1 + (long)row * HDIM;
  int c0 = lane * 8;
  float v[8];
  {
    float4 a0 = *(const float4*)(t0 + c0);
    float4 b0 = *(const float4*)(t0 + c0 + 4);
    float4 a1 = *(const float4*)(t1 + c0);
    float4 b1 = *(const float4*)(t1 + c0 + 4);
    v[0] = a0.x + a1.x; v[1] = a0.y + a1.y; v[2] = a0.z + a1.z; v[3] = a0.w + a1.w;
    v[4] = b0.x + b1.x; v[5] = b0.y + b1.y; v[6] = b0.z + b1.z; v[7] = b0.w + b1.w;
  }
  float sum = 0.0f;
#pragma unroll
  for (int j = 0; j < 8; j++) sum += v[j];
#pragma unroll
  for (int off = 32; off; off >>= 1) sum += __shfl_xor(sum, off);
  float mu = sum * (1.0f / HDIM);
  float sq = 0.0f;
#pragma unroll
  for (int j = 0; j < 8; j++) { float d = v[j] - mu; sq += d * d; }
#pragma unroll
  for (int off = 32; off; off >>= 1) sq += __shfl_xor(sq, off);
  float rs = rsqrtf(sq * (1.0f / HDIM) + 1e-5f);
  const float* xin = Xin + (long)row * HDIM + c0;
  float* xout = Xout + (long)row * HDIM + c0;
  u16 hb[8];
#pragma unroll
  for (int j = 0; j < 8; j++) {
    int c = c0 + j;
    float y = xin[j] + (v[j] - mu) * rs * gamma[c] + beta[c];
    xout[j] = y;
    hb[j] = f2b(y);
  }
  uint4 pk;
  pk.x = hb[0] | ((unsigned)hb[1] << 16);
  pk.y = hb[2] | ((unsigned)hb[3] << 16);
  pk.z = hb[4] | ((unsigned)hb[5] << 16);
  pk.w = hb[6] | ((unsigned)hb[7] << 16);
  *(uint4*)(Xb + (long)row * HDIM + c0) = pk;
}

// ---------------- launch ----------------
extern "C" void kernel_launch(void* const* d_in, const int* in_sizes, int n_in,
                              void* d_out, int out_size, void* d_ws, size_t ws_size,
                              hipStream_t stream) {
  const int*   src   = (const int*)d_in[0];
  const int*   mask  = (const int*)d_in[1];
  const float* emb   = (const float*)d_in[2];
  const float* Wq    = (const float*)d_in[3];
  const float* bq    = (const float*)d_in[4];
  const float* Wk    = (const float*)d_in[5];
  const float* bk    = (const float*)d_in[6];
  const float* Wv    = (const float*)d_in[7];
  const float* bv    = (const float*)d_in[8];
  const float* Wo    = (const float*)d_in[9];
  const float* bo    = (const float*)d_in[10];
  const float* gamma = (const float*)d_in[11];
  const float* beta  = (const float*)d_in[12];
  const float* W1    = (const float*)d_in[13];
  const float* b1    = (const float*)d_in[14];
  const float* W2    = (const float*)d_in[15];
  const float* b2    = (const float*)d_in[16];

  char* ws = (char*)d_ws;
  float* X     = (float*)(ws);                     // 0..8MB   fp32 residual
  u16*   Xb    = (u16*)(ws + (8ll << 20));         // 8..12MB  bf16 mirror
  u16*   QKVb  = (u16*)(ws + (12ll << 20));        // 12..24MB fused QKV bf16
  u16*   Mb    = (u16*)(ws + (12ll << 20));        // 12..28MB FFN mid (reuses QKV+AV)
  u16*   AVb   = (u16*)(ws + (24ll << 20));        // 24..28MB attn out bf16
  float* T     = (float*)(ws + (28ll << 20));      // 28..44MB fp32 partials (2x8MB)
                                                   //   (also attention O-partials)
  u16*   Wqkvt = (u16*)(ws + (44ll << 20));        // 1.5MB
  u16*   Wot   = (u16*)(ws + (45ll << 20) + (512ll << 10)); // 0.5MB
  u16*   W1t   = (u16*)(ws + (46ll << 20));        // 2MB
  u16*   W2t   = (u16*)(ws + (48ll << 20));        // 2MB
  float* bqkv  = (float*)(ws + (50ll << 20));      // 6KB
  u16*   Vtb   = (u16*)(ws + (51ll << 20));        // 4MB V^T [b][h][d][S]
  float* Lpart = (float*)(ws + (55ll << 20));      // 256KB l-partials (2 x 32K floats)
  float* maskf = (float*)(ws + (55ll << 20) + (512ll << 10)); // 16KB
  float* T1    = T + (long)TOKENS * HDIM;

  embed_pe<<<dim3(TOKENS), dim3(64), 0, stream>>>(src, emb, X, Xb);
  mask2f<<<dim3(BATCH * SEQ / 256), 256, 0, stream>>>(mask, maskf);

  for (int i = 0; i < NLAYER; i++) {
    long wo = (long)i * HDIM * HDIM;
    prep_weights<<<dim3(769), 256, 0, stream>>>(
        Wq + wo, Wk + wo, Wv + wo, Wo + wo,
        W1 + (long)i * HDIM * FFND, W2 + (long)i * FFND * HDIM,
        bq + i * HDIM, bk + i * HDIM, bv + i * HDIM,
        Wqkvt, Wot, W1t, W2t, bqkv);

    gemm_tn<128, 1, false, false, true><<<dim3(QSTR / 128, TOKENS / 128), 256, 0, stream>>>(
        Xb, Wqkvt, bqkv, nullptr, QKVb, TOKENS, QSTR, HDIM);

    vtranspose<<<dim3(SEQ / 64, BATCH * NHEAD), 256, 0, stream>>>(QKVb, Vtb);

    attention<<<dim3(SEQ / 64, BATCH * NHEAD, 2), 256, 0, stream>>>(QKVb, Vtb, maskf, T, Lpart);

    attn_combine<<<dim3(TOKENS / 4), 256, 0, stream>>>(T, Lpart, AVb);

    gemm_tn<64, 2, false, true, false><<<dim3(HDIM / 64, TOKENS / 128, 2), 256, 0, stream>>>(
        AVb, Wot, bo + i * HDIM, T, nullptr, TOKENS, HDIM, HDIM);

    ln_residual<<<dim3(TOKENS / 4), 256, 0, stream>>>(X, T, T1, gamma + i * HDIM,
                                                      beta + i * HDIM, X, Xb);

    gemm_tn<128, 1, true, false, true><<<dim3(FFND / 128, TOKENS / 128), 256, 0, stream>>>(
        Xb, W1t, b1 + (long)i * FFND, nullptr, Mb, TOKENS, FFND, HDIM);

    gemm_tn<64, 2, false, true, false><<<dim3(HDIM / 64, TOKENS / 128, 2), 256, 0, stream>>>(
        Mb, W2t, b2 + i * HDIM, T, nullptr, TOKENS, HDIM, FFND);

    ln_residual<<<dim3(TOKENS / 4), 256, 0, stream>>>(X, T, T1, gamma + i * HDIM,
                                                      beta + i * HDIM, X, Xb);
  }

  hipMemcpyAsync(d_out, X, (size_t)TOKENS * HDIM * sizeof(float),
                 hipMemcpyDeviceToDevice, stream);
}

// Round 7
// 1070.153 us; speedup vs baseline: 1.0176x; 1.0176x over previous
//
#include <hip/hip_runtime.h>
#include <math.h>

#define HDIM 512
#define NHEAD 8
#define NLAYER 6
#define SEQ 2048
#define BATCH 2
#define DHEAD 64
#define TOKENS (BATCH*SEQ)
#define FFND (4*HDIM)
#define QSTR 1536   // fused QKV row stride
#define PSTR 88     // P LDS row stride (u16): 44 dwords -> 2-way writes, 16B-aligned reads

typedef unsigned short u16;
typedef __attribute__((ext_vector_type(8))) short short8;
typedef __attribute__((ext_vector_type(4))) float f32x4;

__device__ __forceinline__ u16 f2b(float f) {
  unsigned u = __float_as_uint(f);
  u += 0x7FFFu + ((u >> 16) & 1u);
  return (u16)(u >> 16);
}

__device__ __forceinline__ void gload_lds16(const u16* g, u16* l) {
  __builtin_amdgcn_global_load_lds((const __attribute__((address_space(1))) void*)g,
                                   (__attribute__((address_space(3))) void*)l, 16, 0, 0);
}

// ---------------- embed + positional encoding ----------------
__global__ void embed_pe(const int* __restrict__ src, const float* __restrict__ emb,
                         float* __restrict__ X, u16* __restrict__ Xb) {
  int tok = blockIdx.x;
  int lane = threadIdx.x;           // 64 threads
  int s = tok & (SEQ - 1);
  int c0 = lane * 8;
  const float* e = emb + (long)src[tok] * HDIM + c0;
  float v[8];
#pragma unroll
  for (int j = 0; j < 8; j++) {
    int c = c0 + j;
    float arg = (float)s * exp2f(-(float)(c & ~1) * 0.02595256917f);
    v[j] = e[j] + ((c & 1) ? cosf(arg) : sinf(arg));
  }
  float* xp = X + (long)tok * HDIM + c0;
#pragma unroll
  for (int j = 0; j < 8; j++) xp[j] = v[j];
  u16 hb[8];
#pragma unroll
  for (int j = 0; j < 8; j++) hb[j] = f2b(v[j]);
  uint4 pk;
  pk.x = hb[0] | ((unsigned)hb[1] << 16);
  pk.y = hb[2] | ((unsigned)hb[3] << 16);
  pk.z = hb[4] | ((unsigned)hb[5] << 16);
  pk.w = hb[6] | ((unsigned)hb[7] << 16);
  *(uint4*)(Xb + (long)tok * HDIM + c0) = pk;
}

// ---------------- mask int -> float {0,1} ----------------
__global__ void mask2f(const int* __restrict__ mask, float* __restrict__ maskf) {
  int i = blockIdx.x * 256 + threadIdx.x;
  maskf[i] = (mask[i] == 0) ? 0.0f : 1.0f;
}

// ---------------- per-layer weight prep: fp32 [K][N] -> bf16 [N][K] ----------------
__global__ __launch_bounds__(256) void prep_weights(
    const float* __restrict__ Wq, const float* __restrict__ Wk, const float* __restrict__ Wv,
    const float* __restrict__ Wo, const float* __restrict__ W1, const float* __restrict__ W2,
    const float* __restrict__ bq, const float* __restrict__ bk, const float* __restrict__ bv,
    u16* __restrict__ Wqkvt, u16* __restrict__ Wot, u16* __restrict__ W1t, u16* __restrict__ W2t,
    float* __restrict__ bqkv) {
  int t = blockIdx.x;
  int tid = threadIdx.x;
  if (t == 768) {
    for (int i = tid; i < 1536; i += 256)
      bqkv[i] = (i < 512) ? bq[i] : (i < 1024) ? bk[i - 512] : bv[i - 1024];
    return;
  }
  const float* src; u16* dst; int K, N, kt, nt; long drow0 = 0;
  if (t < 192)      { int m = t / 64, r = t % 64; src = (m==0)?Wq:(m==1)?Wk:Wv; dst = Wqkvt; drow0 = (long)m*512; K=512;  N=512;  kt=r/8;  nt=r%8; }
  else if (t < 256) { int r = t - 192; src = Wo; dst = Wot; K=512;  N=512;  kt=r/8;  nt=r%8; }
  else if (t < 512) { int r = t - 256; src = W1; dst = W1t; K=512;  N=2048; kt=r/32; nt=r%32; }
  else              { int r = t - 512; src = W2; dst = W2t; K=2048; N=512;  kt=r/8;  nt=r%8; }
  __shared__ __align__(16) u16 Lt[64 * 72];
  int kl = tid >> 2;                 // local k row 0..63
#pragma unroll
  for (int rr = 0; rr < 4; rr++) {
    int cl = (tid & 3) * 4 + rr * 16;  // local n col
    float4 v = *(const float4*)(src + (long)(kt * 64 + kl) * N + nt * 64 + cl);
    Lt[(cl + 0) * 72 + kl] = f2b(v.x);
    Lt[(cl + 1) * 72 + kl] = f2b(v.y);
    Lt[(cl + 2) * 72 + kl] = f2b(v.z);
    Lt[(cl + 3) * 72 + kl] = f2b(v.w);
  }
  __syncthreads();
  int nl = tid >> 2;                 // out row (n) 0..63
  int kc = (tid & 3) * 16;           // out col chunk (k)
  u16* dp = dst + (drow0 + nt * 64 + nl) * (long)K + kt * 64 + kc;
  *(uint4*)dp       = *(const uint4*)&Lt[nl * 72 + kc];
  *(uint4*)(dp + 8) = *(const uint4*)&Lt[nl * 72 + kc + 8];
}

// ---------------- V transpose: QKV V-region -> Vtb[b][h][d][S] ----------------
__global__ __launch_bounds__(256) void vtranspose(const u16* __restrict__ QKV,
                                                  u16* __restrict__ Vtb) {
  __shared__ __align__(16) u16 Lt[64 * 72];
  int tid = threadIdx.x;
  int bh = blockIdx.y, b = bh >> 3, h = bh & 7;
  int s0 = blockIdx.x * 64;
  const u16* vsrc = QKV + (long)(b * SEQ + s0) * QSTR + 1024 + h * DHEAD;
  int key = tid >> 2, dc = (tid & 3) * 16;
  const u16* vp = vsrc + (long)key * QSTR + dc;
  uint4 v0 = *(const uint4*)vp;
  uint4 v1 = *(const uint4*)(vp + 8);
  unsigned vr[8] = { v0.x, v0.y, v0.z, v0.w, v1.x, v1.y, v1.z, v1.w };
#pragma unroll
  for (int j = 0; j < 8; j++) {
    Lt[(dc + 2 * j) * 72 + key]     = (u16)vr[j];
    Lt[(dc + 2 * j + 1) * 72 + key] = (u16)(vr[j] >> 16);
  }
  __syncthreads();
  int d = tid >> 2, kc = (tid & 3) * 16;
  u16* dst = Vtb + ((long)bh * DHEAD + d) * SEQ + s0 + kc;
  *(uint4*)dst       = *(const uint4*)&Lt[d * 72 + kc];
  *(uint4*)(dst + 8) = *(const uint4*)&Lt[d * 72 + kc + 8];
}

// ---------------- m97-style bf16 TN GEMM, double-buffered, optional split-K ----------------
template <int BN, int KSPLIT, bool RELU, bool WF32, bool WB16>
__global__ __launch_bounds__(256) void gemm_tn(const u16* __restrict__ A,
                                               const u16* __restrict__ Bt,
                                               const float* __restrict__ bias,
                                               float* __restrict__ Cf,
                                               u16* __restrict__ Cb,
                                               int M, int N, int K) {
  constexpr int NF = BN / 32;                 // n-frags per wave
  __shared__ __align__(16) u16 As[2][128 * 32];
  __shared__ __align__(16) u16 Bs[2][BN * 32];
  int tid = threadIdx.x;
  int wave = tid >> 6, lane = tid & 63;
  int ln = lane & 15, hi = lane >> 4;
  int wm = wave >> 1, wn = wave & 1;
  int m0 = blockIdx.y * 128, n0 = blockIdx.x * BN;
  int z = (KSPLIT > 1) ? blockIdx.z : 0;
  int Ks = K / KSPLIT;
  const u16* Ab = A + z * Ks;
  const u16* Bb = Bt + z * Ks;

  f32x4 acc[4][NF] = {};

  int srow = lane >> 2;        // 0..15
  int skc  = (lane & 3) * 8;   // k-chunk within 32

  auto issue = [&](int kt, int buf) {
    int k0 = kt * 32;
#pragma unroll
    for (int j = 0; j < 2; j++) {
      int row = (wave * 2 + j) * 16 + srow;
      gload_lds16(Ab + (long)(m0 + row) * K + k0 + skc, &As[buf][row * 32 + skc]);
    }
#pragma unroll
    for (int j = 0; j < BN / 64; j++) {
      int row = (wave * (BN / 64) + j) * 16 + srow;
      gload_lds16(Bb + (long)(n0 + row) * K + k0 + skc, &Bs[buf][row * 32 + skc]);
    }
  };

  int NT = Ks / 32;
  issue(0, 0);
  __syncthreads();
  for (int kt = 0; kt < NT; kt++) {
    int buf = kt & 1;
    if (kt + 1 < NT) issue(kt + 1, buf ^ 1);
    short8 af[4], bf[NF];
#pragma unroll
    for (int mt = 0; mt < 4; mt++)
      af[mt] = *(const short8*)&As[buf][(wm * 64 + mt * 16 + ln) * 32 + 8 * hi];
#pragma unroll
    for (int nt = 0; nt < NF; nt++)
      bf[nt] = *(const short8*)&Bs[buf][(wn * (BN / 2) + nt * 16 + ln) * 32 + 8 * hi];
#pragma unroll
    for (int mt = 0; mt < 4; mt++)
#pragma unroll
      for (int nt = 0; nt < NF; nt++)
        acc[mt][nt] = __builtin_amdgcn_mfma_f32_16x16x32_bf16(af[mt], bf[nt], acc[mt][nt], 0, 0, 0);
    __syncthreads();
  }

  float* Cz = WF32 ? (Cf + (long)z * M * N) : nullptr;
#pragma unroll
  for (int mt = 0; mt < 4; mt++)
#pragma unroll
    for (int nt = 0; nt < NF; nt++)
#pragma unroll
      for (int r = 0; r < 4; r++) {
        int row = m0 + wm * 64 + mt * 16 + hi * 4 + r;
        int col = n0 + wn * (BN / 2) + nt * 16 + ln;
        float v = acc[mt][nt][r];
        if (KSPLIT == 1 || z == 0) v += bias[col];
        if (RELU) v = fmaxf(v, 0.0f);
        if (WF32) Cz[(long)row * N + col] = v;
        if (WB16) Cb[(long)row * N + col] = f2b(v);
      }
}

// ---------------- flash attention: S^T form, XCD-local grid ----------------
// grid (BH=16, SEQ/64=32): linear block id = bh + 16*qtile -> XCD = bh%8 (round
// robin), so each XCD serves 2 heads (~1MB KV) -> L2-resident KV stream.
// Wave w owns q-rows q0..q0+15. QK^T computed as S^T (A=K,B=Q); lane holds 4
// CONSECUTIVE keys -> one ds_write_b64 per frag at stride 88 (2-way, free).
// No-max exact softmax (scores bounded); l reduced once after the loop.
__global__ __launch_bounds__(256) void attention(const u16* __restrict__ QKV,
                                                 const u16* __restrict__ Vtb,
                                                 const float* __restrict__ maskf,
                                                 u16* __restrict__ Og) {
  __shared__ __align__(16) u16 Ks[2][2][64 * 32];  // [buf][d-half][key][32]
  __shared__ __align__(16) u16 Vs[2][2][64 * 32];  // [buf][key-half][d][32]
  __shared__ __align__(16) u16 P[4 * 16 * PSTR];   // per-wave P[q][key]
  int tid = threadIdx.x, w = tid >> 6, lane = tid & 63;
  int ln = lane & 15, hi = lane >> 4;
  int bh = blockIdx.x, b = bh >> 3, h = bh & 7;
  int q0 = blockIdx.y * 64 + w * 16;
  const u16* qbase = QKV + (long)b * SEQ * QSTR + h * DHEAD;
  const u16* kbase = qbase + 512;
  const u16* vtbase = Vtb + (long)bh * DHEAD * SEQ;
  const float* mbase = maskf + b * SEQ;
  u16* Pw = P + w * 16 * PSTR;

  short8 qf[2];
#pragma unroll
  for (int ks = 0; ks < 2; ks++)
    qf[ks] = *(const short8*)(qbase + (long)(q0 + ln) * QSTR + ks * 32 + 8 * hi);

  f32x4 o[4] = {};
  float lsum = 0.0f;

  int srow = w * 16 + (lane >> 2);   // 0..63 across waves
  int sc = (lane & 3) * 8;           // 8-u16 chunk

  auto issue = [&](int t, int buf) {
    long kk = (long)t * 64;
    const u16* kg = kbase + (kk + srow) * QSTR + sc;
    gload_lds16(kg,      &Ks[buf][0][srow * 32 + sc]);
    gload_lds16(kg + 32, &Ks[buf][1][srow * 32 + sc]);
    const u16* vg = vtbase + (long)srow * SEQ + kk + sc;
    gload_lds16(vg,      &Vs[buf][0][srow * 32 + sc]);
    gload_lds16(vg + 32, &Vs[buf][1][srow * 32 + sc]);
  };

  const int NT = SEQ / 64;
  issue(0, 0);
  __syncthreads();
  for (int t = 0; t < NT; t++) {
    int buf = t & 1;
    if (t + 1 < NT) issue(t + 1, buf ^ 1);
    int k0 = t * 64;

    // S^T = K @ Q^T : lane(ln,hi) reg r -> key = nt*16 + hi*4 + r, q = ln.
    f32x4 s[4] = {};
#pragma unroll
    for (int ks = 0; ks < 2; ks++)
#pragma unroll
      for (int nt = 0; nt < 4; nt++) {
        short8 kf = *(const short8*)&Ks[buf][ks][(nt * 16 + ln) * 32 + 8 * hi];
        s[nt] = __builtin_amdgcn_mfma_f32_16x16x32_bf16(kf, qf[ks], s[nt], 0, 0, 0);
      }
#pragma unroll
    for (int nt = 0; nt < 4; nt++) {
      float4 mf = *(const float4*)(mbase + k0 + nt * 16 + hi * 4);
      float mfa[4] = { mf.x, mf.y, mf.z, mf.w };
      u16 hb[4];
#pragma unroll
      for (int r = 0; r < 4; r++) {
        float p = __expf(s[nt][r] * 0.125f) * mfa[r];
        lsum += p;
        hb[r] = f2b(p);
      }
      uint2 pk;
      pk.x = hb[0] | ((unsigned)hb[1] << 16);
      pk.y = hb[2] | ((unsigned)hb[3] << 16);
      *(uint2*)&Pw[ln * PSTR + nt * 16 + hi * 4] = pk;
    }
    // O += P @ V  (A-frag read of P[q][key]; same-wave ordering via lgkmcnt)
    short8 pa[2];
#pragma unroll
    for (int ka = 0; ka < 2; ka++)
      pa[ka] = *(const short8*)&Pw[ln * PSTR + ka * 32 + 8 * hi];
#pragma unroll
    for (int nt = 0; nt < 4; nt++) {
      short8 bv0 = *(const short8*)&Vs[buf][0][(nt * 16 + ln) * 32 + 8 * hi];
      short8 bv1 = *(const short8*)&Vs[buf][1][(nt * 16 + ln) * 32 + 8 * hi];
      o[nt] = __builtin_amdgcn_mfma_f32_16x16x32_bf16(pa[0], bv0, o[nt], 0, 0, 0);
      o[nt] = __builtin_amdgcn_mfma_f32_16x16x32_bf16(pa[1], bv1, o[nt], 0, 0, 0);
    }
    __syncthreads();
  }

  // l[q=ln] = sum over hi-groups; then fetch l for q=hi*4+r via shfl
  lsum += __shfl_xor(lsum, 16);
  lsum += __shfl_xor(lsum, 32);
  float inv[4];
#pragma unroll
  for (int r = 0; r < 4; r++)
    inv[r] = 1.0f / __shfl(lsum, hi * 4 + r);

  u16* obase = Og + (long)b * SEQ * HDIM + h * DHEAD;
#pragma unroll
  for (int r = 0; r < 4; r++) {
    int srow2 = q0 + hi * 4 + r;
#pragma unroll
    for (int nt = 0; nt < 4; nt++)
      obase[(long)srow2 * HDIM + nt * 16 + ln] = f2b(o[nt][r] * inv[r]);
  }
}

// ---------------- residual + LayerNorm over summed split-K partials ----------------
__global__ __launch_bounds__(256) void ln_residual(const float* __restrict__ Xin,
                                                   const float* __restrict__ T0,
                                                   const float* __restrict__ T1,
                                                   const float* __restrict__ gamma,
                                                   const float* __restrict__ beta,
                                                   float* __restrict__ Xout,
                                                   u16* __restrict__ Xb) {
  int tid = threadIdx.x, w = tid >> 6, lane = tid & 63;
  int row = blockIdx.x * 4 + w;
  const float* t0 = T0 + (long)row * HDIM;
  const float* t1 = T1 + (long)row * HDIM;
  int c0 = lane * 8;
  float v[8];
  {
    float4 a0 = *(const float4*)(t0 + c0);
    float4 b0 = *(const float4*)(t0 + c0 + 4);
    float4 a1 = *(const float4*)(t1 + c0);
    float4 b1 = *(const float4*)(t1 + c0 + 4);
    v[0] = a0.x + a1.x; v[1] = a0.y + a1.y; v[2] = a0.z + a1.z; v[3] = a0.w + a1.w;
    v[4] = b0.x + b1.x; v[5] = b0.y + b1.y; v[6] = b0.z + b1.z; v[7] = b0.w + b1.w;
  }
  float sum = 0.0f;
#pragma unroll
  for (int j = 0; j < 8; j++) sum += v[j];
#pragma unroll
  for (int off = 32; off; off >>= 1) sum += __shfl_xor(sum, off);
  float mu = sum * (1.0f / HDIM);
  float sq = 0.0f;
#pragma unroll
  for (int j = 0; j < 8; j++) { float d = v[j] - mu; sq += d * d; }
#pragma unroll
  for (int off = 32; off; off >>= 1) sq += __shfl_xor(sq, off);
  float rs = rsqrtf(sq * (1.0f / HDIM) + 1e-5f);
  const float* xin = Xin + (long)row * HDIM + c0;
  float* xout = Xout + (long)row * HDIM + c0;
  u16 hb[8];
#pragma unroll
  for (int j = 0; j < 8; j++) {
    int c = c0 + j;
    float y = xin[j] + (v[j] - mu) * rs * gamma[c] + beta[c];
    xout[j] = y;
    hb[j] = f2b(y);
  }
  uint4 pk;
  pk.x = hb[0] | ((unsigned)hb[1] << 16);
  pk.y = hb[2] | ((unsigned)hb[3] << 16);
  pk.z = hb[4] | ((unsigned)hb[5] << 16);
  pk.w = hb[6] | ((unsigned)hb[7] << 16);
  *(uint4*)(Xb + (long)row * HDIM + c0) = pk;
}

// ---------------- launch ----------------
extern "C" void kernel_launch(void* const* d_in, const int* in_sizes, int n_in,
                              void* d_out, int out_size, void* d_ws, size_t ws_size,
                              hipStream_t stream) {
  const int*   src   = (const int*)d_in[0];
  const int*   mask  = (const int*)d_in[1];
  const float* emb   = (const float*)d_in[2];
  const float* Wq    = (const float*)d_in[3];
  const float* bq    = (const float*)d_in[4];
  const float* Wk    = (const float*)d_in[5];
  const float* bk    = (const float*)d_in[6];
  const float* Wv    = (const float*)d_in[7];
  const float* bv    = (const float*)d_in[8];
  const float* Wo    = (const float*)d_in[9];
  const float* bo    = (const float*)d_in[10];
  const float* gamma = (const float*)d_in[11];
  const float* beta  = (const float*)d_in[12];
  const float* W1    = (const float*)d_in[13];
  const float* b1    = (const float*)d_in[14];
  const float* W2    = (const float*)d_in[15];
  const float* b2    = (const float*)d_in[16];

  char* ws = (char*)d_ws;
  float* X     = (float*)(ws);                     // 0..8MB   fp32 residual
  u16*   Xb    = (u16*)(ws + (8ll << 20));         // 8..12MB  bf16 mirror
  u16*   QKVb  = (u16*)(ws + (12ll << 20));        // 12..24MB fused QKV bf16
  u16*   Mb    = (u16*)(ws + (12ll << 20));        // 12..28MB FFN mid (reuses QKV+AV)
  u16*   AVb   = (u16*)(ws + (24ll << 20));        // 24..28MB attn out bf16
  float* T     = (float*)(ws + (28ll << 20));      // 28..44MB fp32 split-K partials (2x8MB)
  u16*   Wqkvt = (u16*)(ws + (44ll << 20));        // 1.5MB
  u16*   Wot   = (u16*)(ws + (45ll << 20) + (512ll << 10)); // 0.5MB
  u16*   W1t   = (u16*)(ws + (46ll << 20));        // 2MB
  u16*   W2t   = (u16*)(ws + (48ll << 20));        // 2MB
  float* bqkv  = (float*)(ws + (50ll << 20));      // 6KB
  u16*   Vtb   = (u16*)(ws + (51ll << 20));        // 4MB V^T [b][h][d][S]
  float* maskf = (float*)(ws + (55ll << 20));      // 16KB
  float* T1    = T + (long)TOKENS * HDIM;

  embed_pe<<<dim3(TOKENS), dim3(64), 0, stream>>>(src, emb, X, Xb);
  mask2f<<<dim3(BATCH * SEQ / 256), 256, 0, stream>>>(mask, maskf);

  for (int i = 0; i < NLAYER; i++) {
    long wo = (long)i * HDIM * HDIM;
    prep_weights<<<dim3(769), 256, 0, stream>>>(
        Wq + wo, Wk + wo, Wv + wo, Wo + wo,
        W1 + (long)i * HDIM * FFND, W2 + (long)i * FFND * HDIM,
        bq + i * HDIM, bk + i * HDIM, bv + i * HDIM,
        Wqkvt, Wot, W1t, W2t, bqkv);

    gemm_tn<128, 1, false, false, true><<<dim3(QSTR / 128, TOKENS / 128), 256, 0, stream>>>(
        Xb, Wqkvt, bqkv, nullptr, QKVb, TOKENS, QSTR, HDIM);

    vtranspose<<<dim3(SEQ / 64, BATCH * NHEAD), 256, 0, stream>>>(QKVb, Vtb);

    attention<<<dim3(BATCH * NHEAD, SEQ / 64), 256, 0, stream>>>(QKVb, Vtb, maskf, AVb);

    gemm_tn<64, 2, false, true, false><<<dim3(HDIM / 64, TOKENS / 128, 2), 256, 0, stream>>>(
        AVb, Wot, bo + i * HDIM, T, nullptr, TOKENS, HDIM, HDIM);

    ln_residual<<<dim3(TOKENS / 4), 256, 0, stream>>>(X, T, T1, gamma + i * HDIM,
                                                      beta + i * HDIM, X, Xb);

    gemm_tn<128, 1, true, false, true><<<dim3(FFND / 128, TOKENS / 128), 256, 0, stream>>>(
        Xb, W1t, b1 + (long)i * FFND, nullptr, Mb, TOKENS, FFND, HDIM);

    gemm_tn<64, 2, false, true, false><<<dim3(HDIM / 64, TOKENS / 128, 2), 256, 0, stream>>>(
        Mb, W2t, b2 + i * HDIM, T, nullptr, TOKENS, HDIM, FFND);

    ln_residual<<<dim3(TOKENS / 4), 256, 0, stream>>>(X, T, T1, gamma + i * HDIM,
                                                      beta + i * HDIM, X, Xb);
  }

  hipMemcpyAsync(d_out, X, (size_t)TOKENS * HDIM * sizeof(float),
                 hipMemcpyDeviceToDevice, stream);
}